// Round 13
// baseline (828.399 us; speedup 1.0000x reference)
//
#include <hip/hip_runtime.h>
#include <hip/hip_bf16.h>

#define T_TOK 4096
#define H_DIM 4096
#define I_DIM 2048
#define N_EXP 8
#define TOPK  2
#define NPAIR (T_TOK*TOPK)          // 8192
#define BM    128
#define BK    32
#define MAXT  (NPAIR/BM + N_EXP)    // 72
#define BM1   256
#define BN1   128
#define MAXT1 (NPAIR/BM1 + N_EXP)   // 40

// ---- workspace offsets (bytes) ----
#define HT_OFF   ((size_t)1 << 20)                  // Ht128: 37.7MB
#define W0_OFF   ((size_t)44 << 20)                 // Wot128: 134MB (written AFTER gemm1f)
#define AT_OFF   ((size_t)44 << 20)                 // At128: 72MB (dead after gemm1f)
#define WS_OFF   ((size_t)120 << 20)                // Ws paired bf16: 268MB (dead after gemm1f)
#define NEED_NEW (WS_OFF + 268435456ull)            // ~376 MiB

typedef __attribute__((ext_vector_type(8))) short  bf16x8;
typedef __attribute__((ext_vector_type(4))) float  f32x4v;

__device__ __forceinline__ short f2bf(float f) {
    __hip_bfloat16 h = __float2bfloat16(f);
    return __builtin_bit_cast(short, h);
}
__device__ __forceinline__ float bf2f(short s) {
    unsigned int u = ((unsigned int)(unsigned short)s) << 16;
    return __builtin_bit_cast(float, u);
}

__device__ __forceinline__ bf16x8 pack8(f32x4v a, f32x4v b) {
    bf16x8 r;
    r[0]=f2bf(a[0]); r[1]=f2bf(a[1]); r[2]=f2bf(a[2]); r[3]=f2bf(a[3]);
    r[4]=f2bf(b[0]); r[5]=f2bf(b[1]); r[6]=f2bf(b[2]); r[7]=f2bf(b[3]);
    return r;
}

__device__ __forceinline__ void load_lds16(const short* g, short* l) {
    __builtin_amdgcn_global_load_lds(
        (const __attribute__((address_space(1))) void*)g,
        (__attribute__((address_space(3))) void*)l, 16, 0, 0);
}

// ---------------- fp32 -> bf16 plain (fallback X path) ----------------
__global__ void cvt_kernel(const float* __restrict__ X, short* __restrict__ Xbf) {
    const size_t i = ((size_t)blockIdx.x * 256 + threadIdx.x) * 8;
    f32x4v a = *(const f32x4v*)(X + i);
    f32x4v b = *(const f32x4v*)(X + i + 4);
    *(bf16x8*)(Xbf + i) = pack8(a, b);
}

// ---------------- routing ----------------
__global__ void route_kernel(const int* __restrict__ ids, const float* __restrict__ wts,
                             int* __restrict__ pair_token, float* __restrict__ pair_w,
                             int* __restrict__ tile_expert, int* __restrict__ tile_row0,
                             int* __restrict__ tile_rows,
                             int* __restrict__ t1_expert, int* __restrict__ t1_row0,
                             int* __restrict__ t1_rows)
{
    __shared__ int scn[256][N_EXP];
    const int tid = threadIdx.x;
    const int PPT = NPAIR / 256;
    const int base = tid * PPT;

    int c[N_EXP], orig[N_EXP];
    #pragma unroll
    for (int e = 0; e < N_EXP; ++e) c[e] = 0;
    for (int p = 0; p < PPT; ++p) c[ids[base + p]]++;
    #pragma unroll
    for (int e = 0; e < N_EXP; ++e) { orig[e] = c[e]; scn[tid][e] = c[e]; }
    __syncthreads();

    for (int off = 1; off < 256; off <<= 1) {
        int add[N_EXP];
        #pragma unroll
        for (int e = 0; e < N_EXP; ++e) add[e] = (tid >= off) ? scn[tid - off][e] : 0;
        __syncthreads();
        #pragma unroll
        for (int e = 0; e < N_EXP; ++e) { c[e] += add[e]; scn[tid][e] = c[e]; }
        __syncthreads();
    }

    int segs[N_EXP + 1];
    {
        int run = 0;
        #pragma unroll
        for (int e = 0; e < N_EXP; ++e) { segs[e] = run; run += scn[255][e]; }
        segs[N_EXP] = run;
    }
    int pos[N_EXP];
    #pragma unroll
    for (int e = 0; e < N_EXP; ++e) pos[e] = segs[e] + c[e] - orig[e];

    for (int p = 0; p < PPT; ++p) {
        int pp = base + p;
        int e = ids[pp];
        int q = pos[e]++;
        pair_token[q] = pp / TOPK;
        pair_w[q]     = wts[pp];
    }

    if (tid == 0) {
        int t = 0;
        for (int e = 0; e < N_EXP; ++e) {
            int s = segs[e], en = segs[e + 1];
            for (int r = s; r < en; r += BM) {
                tile_expert[t] = e; tile_row0[t] = r; tile_rows[t] = min(BM, en - r); ++t;
            }
        }
        for (; t < MAXT; ++t) { tile_expert[t] = 0; tile_row0[t] = 0; tile_rows[t] = 0; }

        t = 0;
        for (int e = 0; e < N_EXP; ++e) {
            int s = segs[e], en = segs[e + 1];
            for (int r = s; r < en; r += BM1) {
                t1_expert[t] = e; t1_row0[t] = r; t1_rows[t] = min(BM1, en - r); ++t;
            }
        }
        for (; t < MAXT1; ++t) { t1_expert[t] = 0; t1_row0[t] = 0; t1_rows[t] = 0; }
    }
}

// ================= coalesced LDS-transpose preps =================
#define PRP 132

// Paired Wi -> Ws [e][slice 32][kt 64][q 8][panel-row 128][x 8]
//   panel row p: g=p>>6 (64-col group), q=(p>>5)&1 (0=gate/Wi0, 1=up/Wi1), c=p&31
//   source row = slice*64 + g*32 + c of Wi_q[e]
__global__ __launch_bounds__(256) void wsprep_kernel(const float* __restrict__ Wi0,
                                                     const float* __restrict__ Wi1,
                                                     short* __restrict__ Ws) {
    const int bid = blockIdx.x;          // 8 * 32 * 32 = 8192
    const int e   = bid >> 10;
    const int nt  = (bid >> 5) & 31;     // slice
    const int ktg = bid & 31;
    __shared__ short lds[128][PRP];
    const int tid = threadIdx.x;
    #pragma unroll
    for (int it = 0; it < 8; ++it) {
        int r  = it * 16 + (tid >> 4);   // panel row 0..127
        int hc = (tid & 15) * 8;
        int g  = r >> 6;
        int q  = (r >> 5) & 1;
        int c  = r & 31;
        const float* W = q ? Wi1 : Wi0;
        const float* s = W + ((size_t)e * 2048 + nt * 64 + g * 32 + c) * 4096 + ktg * 128 + hc;
        f32x4v a = *(const f32x4v*)s;
        f32x4v b = *(const f32x4v*)(s + 4);
        *(bf16x8*)&lds[r][hc] = pack8(a, b);
    }
    __syncthreads();
    short* dst = Ws + ((size_t)(e * 32 + nt)) * 524288 + (size_t)ktg * 2 * 8192;
    #pragma unroll
    for (int it = 0; it < 8; ++it) {
        int idx = it * 256 + tid;
        int c8  = idx >> 7;
        int r   = idx & 127;
        bf16x8 v = *(const bf16x8*)&lds[r][c8 * 8];
        *(bf16x8*)(dst + (size_t)(c8 >> 3) * 8192 + (c8 & 7) * 1024 + r * 8) = v;
    }
}

// X gather -> At128 [tile 72][kt 64][q 8][r 128][x 8]
__global__ __launch_bounds__(256) void aprep128_kernel(const float* __restrict__ X,
                             const int* __restrict__ pair_token,
                             const int* __restrict__ tile_row0, const int* __restrict__ tile_rows,
                             short* __restrict__ At) {
    const int bid  = blockIdx.x;         // 72 * 32 = 2304
    const int tile = bid >> 5;
    const int ktg  = bid & 31;
    const int rows = tile_rows[tile];
    if (rows == 0) return;
    const int row0 = tile_row0[tile];
    __shared__ short lds[128][PRP];
    const int tid = threadIdx.x;
    #pragma unroll
    for (int it = 0; it < 8; ++it) {
        int r  = it * 16 + (tid >> 4);
        int hc = (tid & 15) * 8;
        int tok = pair_token[row0 + min(r, rows - 1)];
        const float* s = X + (size_t)tok * 4096 + ktg * 128 + hc;
        f32x4v a = *(const f32x4v*)s;
        f32x4v b = *(const f32x4v*)(s + 4);
        *(bf16x8*)&lds[r][hc] = pack8(a, b);
    }
    __syncthreads();
    short* dst = At + (size_t)tile * 524288 + (size_t)ktg * 2 * 8192;
    #pragma unroll
    for (int it = 0; it < 8; ++it) {
        int idx = it * 256 + tid;
        int c8  = idx >> 7;
        int r   = idx & 127;
        bf16x8 v = *(const bf16x8*)&lds[r][c8 * 8];
        *(bf16x8*)(dst + (size_t)(c8 >> 3) * 8192 + (c8 & 7) * 1024 + r * 8) = v;
    }
}

// Wo (E,H,I) fp32 -> Wot128 [e][hb 32][kt 32][q 8][r 128][x 8]
__global__ __launch_bounds__(256) void woprep2_kernel(const float* __restrict__ W, short* __restrict__ Wt) {
    const int bid = blockIdx.x;          // 4096
    const int e   = bid >> 9;
    const int hb  = (bid >> 4) & 31;
    const int ktg = bid & 15;
    __shared__ short lds[128][PRP];
    const int tid = threadIdx.x;
    const float* src0 = W + ((size_t)(e * 4096 + hb * 128)) * 2048 + ktg * 128;
    #pragma unroll
    for (int it = 0; it < 8; ++it) {
        int r  = it * 16 + (tid >> 4);
        int hc = (tid & 15) * 8;
        const float* s = src0 + (size_t)r * 2048 + hc;
        f32x4v a = *(const f32x4v*)s;
        f32x4v b = *(const f32x4v*)(s + 4);
        *(bf16x8*)&lds[r][hc] = pack8(a, b);
    }
    __syncthreads();
    short* dst = Wt + ((size_t)(e * 32 + hb)) * 262144 + (size_t)ktg * 2 * 8192;
    #pragma unroll
    for (int it = 0; it < 8; ++it) {
        int idx = it * 256 + tid;
        int c8  = idx >> 7;
        int r   = idx & 127;
        bf16x8 v = *(const bf16x8*)&lds[r][c8 * 8];
        *(bf16x8*)(dst + (size_t)(c8 >> 3) * 8192 + (c8 & 7) * 1024 + r * 8) = v;
    }
}

// ================= GEMM1f: fused gate/up + silu, 128x128 tile, BK=64, 64x64 wave quadrants =================
// Wave (wr,wc) owns rows wr*64..+63 x panel cols wc*64..+63. Panel col group [32 gate | 32 up]:
// nf0-1 = gate cols, nf2-3 = up of SAME I-cols, same lane -> in-reg silu.
__global__ __launch_bounds__(256, 3) void gemm1f_kernel(
    const short* __restrict__ At,       // [72][64][8][128][8]
    const short* __restrict__ Ws,       // [E][32][64][8][128 paired][8]
    const float* __restrict__ pair_w,
    const int* __restrict__ tile_expert, const int* __restrict__ tile_row0,
    const int* __restrict__ tile_rows,
    short* __restrict__ Ht)             // [72][32][8][128][8]
{
    const int b   = blockIdx.x;          // 2304 = 72*32
    const int l   = (b & 7) * 288 + (b >> 3);
    const int tile  = l >> 5;
    const int n0idx = l & 31;            // I-slice of 64
    const int rows = tile_rows[tile];
    if (rows == 0) return;
    const int e    = tile_expert[tile];
    const int row0 = tile_row0[tile];

    __shared__ short sAB[2048 * 8];      // 32 KB
    __shared__ float sPw[128];

    const int tid  = threadIdx.x;
    const int lane = tid & 63;
    const int w    = tid >> 6;

    if (tid < 128) sPw[tid] = (tid < rows) ? pair_w[row0 + tid] : 0.f;
    __syncthreads();

    const short* aT = At + (size_t)tile * 524288;
    const short* bT = Ws + ((size_t)e * 32 + n0idx) * 524288;

    const int wr = w >> 1, wc = w & 1;
    const int frow = lane & 15, fsel = lane >> 4;

    f32x4v acc[4][4];
    #pragma unroll
    for (int mf = 0; mf < 4; ++mf)
        #pragma unroll
        for (int nf = 0; nf < 4; ++nf) acc[mf][nf] = (f32x4v)0.f;

    const int KT = H_DIM / 64;           // 64
    for (int kt = 0; kt < KT; ++kt) {
        __syncthreads();
        {
            const size_t ko = (size_t)kt * 8192;
            #pragma unroll
            for (int i = 0; i < 4; ++i) {
                load_lds16(aT + ko + (size_t)tid * 8 + i * 2048,
                           &sAB[(i * 256 + w * 64) * 8]);
                load_lds16(bT + ko + (size_t)tid * 8 + i * 2048,
                           &sAB[((1024 + i * 256 + w * 64)) * 8]);
            }
        }
        __syncthreads();

        #pragma unroll
        for (int h = 0; h < 2; ++h) {
            const int c = h * 4 + fsel;
            bf16x8 af[4];
            #pragma unroll
            for (int mf = 0; mf < 4; ++mf)
                af[mf] = *(const bf16x8*)&sAB[(c * 128 + wr * 64 + mf * 16 + frow) * 8];
            #pragma unroll
            for (int nf = 0; nf < 4; ++nf) {
                bf16x8 bf = *(const bf16x8*)&sAB[(1024 + c * 128 + wc * 64 + nf * 16 + frow) * 8];
                #pragma unroll
                for (int mf = 0; mf < 4; ++mf)
                    acc[mf][nf] = __builtin_amdgcn_mfma_f32_16x16x32_bf16(af[mf], bf, acc[mf][nf], 0, 0, 0);
            }
        }
    }

    // fused epilogue: gate=acc[mf][nfg], up=acc[mf][nfg+2] -> silu*pw -> Ht
    #pragma unroll
    for (int mf = 0; mf < 4; ++mf)
        #pragma unroll
        for (int nfg = 0; nfg < 2; ++nfg) {
            const int c_g = n0idx * 64 + wc * 32 + nfg * 16 + frow;   // I-col
            const size_t cb = (size_t)tile * 262144 + (size_t)(c_g >> 6) * 8192
                            + ((c_g >> 3) & 7) * 1024 + (c_g & 7);
            #pragma unroll
            for (int j = 0; j < 4; ++j) {
                int row = wr * 64 + mf * 16 + fsel * 4 + j;
                if (row < rows) {
                    float g = acc[mf][nfg][j];
                    float u = acc[mf][nfg + 2][j];
                    float sig = 1.f / (1.f + __expf(-g));
                    Ht[cb + (size_t)row * 8] = f2bf(g * sig * u * sPw[row]);
                }
            }
        }
}

// ================= GEMM2s: 128x128 tile, BK=64, m97 shape (proven R11) =================
__global__ __launch_bounds__(256, 3) void gemm2s_kernel(
    const short* __restrict__ Ht,       // [72][32][8][128][8]
    const short* __restrict__ Wot,      // [E][32][32][8][128][8]
    const int* __restrict__ pair_token,
    const int* __restrict__ tile_expert, const int* __restrict__ tile_row0,
    const int* __restrict__ tile_rows,
    float* __restrict__ out)            // [T][H]
{
    const int b   = blockIdx.x;          // 2304 = 72*32
    const int l   = (b & 7) * 288 + (b >> 3);
    const int tile  = l >> 5;
    const int n0idx = l & 31;            // over H/128
    const int rows = tile_rows[tile];
    if (rows == 0) return;
    const int e    = tile_expert[tile];
    const int row0 = tile_row0[tile];

    __shared__ short sAB[2048 * 8];      // 32 KB
    __shared__ int   sTok[128];

    const int tid  = threadIdx.x;
    const int lane = tid & 63;
    const int w    = tid >> 6;

    if (tid < 128) sTok[tid] = pair_token[row0 + min(tid, rows - 1)];
    __syncthreads();

    const short* aT = Ht  + (size_t)tile * 262144;
    const short* bT = Wot + ((size_t)e * 32 + n0idx) * 262144;

    const int wr = w >> 1, wc = w & 1;
    const int frow = lane & 15, fsel = lane >> 4;

    f32x4v acc[4][4];
    #pragma unroll
    for (int mf = 0; mf < 4; ++mf)
        #pragma unroll
        for (int nf = 0; nf < 4; ++nf) acc[mf][nf] = (f32x4v)0.f;

    const int KT = I_DIM / 64;           // 32
    for (int kt = 0; kt < KT; ++kt) {
        __syncthreads();
        {
            const size_t ko = (size_t)kt * 8192;
            #pragma unroll
            for (int i = 0; i < 4; ++i) {
                load_lds16(aT + ko + (size_t)tid * 8 + i * 2048,
                           &sAB[(i * 256 + w * 64) * 8]);
                load_lds16(bT + ko + (size_t)tid * 8 + i * 2048,
                           &sAB[((1024 + i * 256 + w * 64)) * 8]);
            }
        }
        __syncthreads();

        #pragma unroll
        for (int h = 0; h < 2; ++h) {
            const int c = h * 4 + fsel;
            bf16x8 af[4];
            #pragma unroll
            for (int mf = 0; mf < 4; ++mf)
                af[mf] = *(const bf16x8*)&sAB[(c * 128 + wr * 64 + mf * 16 + frow) * 8];
            #pragma unroll
            for (int nf = 0; nf < 4; ++nf) {
                bf16x8 bf = *(const bf16x8*)&sAB[(1024 + c * 128 + wc * 64 + nf * 16 + frow) * 8];
                #pragma unroll
                for (int mf = 0; mf < 4; ++mf)
                    acc[mf][nf] = __builtin_amdgcn_mfma_f32_16x16x32_bf16(af[mf], bf, acc[mf][nf], 0, 0, 0);
            }
        }
    }

    const int r4 = fsel * 4;
    #pragma unroll
    for (int mf = 0; mf < 4; ++mf)
        #pragma unroll
        for (int nf = 0; nf < 4; ++nf) {
            const int col = n0idx * 128 + wc * 64 + nf * 16 + frow;
            #pragma unroll
            for (int j = 0; j < 4; ++j) {
                int rr = wr * 64 + mf * 16 + r4 + j;
                if (rr < rows)
                    atomicAdd(out + (size_t)sTok[rr] * H_DIM + col, acc[mf][nf][j]);
            }
        }
}

// ================= FALLBACK PATH (R3) =================
__global__ __launch_bounds__(512, 2) void gemm1_kernel(
    const short* __restrict__ Xbf, const float* __restrict__ Wi0, const float* __restrict__ Wi1,
    const int* __restrict__ pair_token, const float* __restrict__ pair_w,
    const int* __restrict__ t1_expert, const int* __restrict__ t1_row0, const int* __restrict__ t1_rows,
    short* __restrict__ Hbuf)
{
    const int tile = blockIdx.x;
    const int rows = t1_rows[tile];
    if (rows == 0) return;
    const int e    = t1_expert[tile];
    const int row0 = t1_row0[tile];
    const int n0   = blockIdx.y * BN1;

    __shared__ short sA [2][BM1][64];
    __shared__ short sB0[2][BN1][64 + 8];
    __shared__ short sB1[2][BN1][64 + 8];
    __shared__ int   sTok[BM1];
    __shared__ float sPw [BM1];

    const int tid  = threadIdx.x;
    const int lane = tid & 63;
    const int w    = tid >> 6;

    if (tid < BM1) {
        int tr = min(tid, rows - 1);
        sTok[tid] = pair_token[row0 + tr];
        sPw[tid]  = (tid < rows) ? pair_w[row0 + tid] : 0.f;
    }
    __syncthreads();

    const short* aSrc[4];
    #pragma unroll
    for (int i = 0; i < 4; ++i) {
        int r = w * 32 + i * 8 + (lane >> 3);
        int j = lane & 7;
        aSrc[i] = Xbf + (size_t)sTok[r] * H_DIM + ((j ^ (r & 7)) * 8);
    }

    const int brow = tid >> 2;
    const int bq   = tid & 3;
    const size_t wboff = ((size_t)e * I_DIM + (n0 + brow)) * H_DIM + bq * 16;
    const float* b0p = Wi0 + wboff;
    const float* b1p = Wi1 + wboff;

    const int wr   = w >> 1;
    const int wc   = w & 1;
    const int frow = lane & 15;
    const int fsel = lane >> 4;

    f32x4v accg[4][4], accu[4][4];
    #pragma unroll
    for (int mf = 0; mf < 4; ++mf)
        #pragma unroll
        for (int nf = 0; nf < 4; ++nf) { accg[mf][nf] = (f32x4v)0.f; accu[mf][nf] = (f32x4v)0.f; }

    f32x4v rb0[4], rb1[4];

    #pragma unroll
    for (int i = 0; i < 4; ++i)
        load_lds16(aSrc[i], &sA[0][w * 32 + i * 8][0]);
    #pragma unroll
    for (int i = 0; i < 4; ++i) { rb0[i] = *(const f32x4v*)(b0p + i * 4); rb1[i] = *(const f32x4v*)(b1p + i * 4); }
    {
        short* d0 = &sB0[0][brow][bq * 16];
        *(bf16x8*)d0       = pack8(rb0[0], rb0[1]);
        *(bf16x8*)(d0 + 8) = pack8(rb0[2], rb0[3]);
        short* d1 = &sB1[0][brow][bq * 16];
        *(bf16x8*)d1       = pack8(rb1[0], rb1[1]);
        *(bf16x8*)(d1 + 8) = pack8(rb1[2], rb1[3]);
    }
    __syncthreads();

    const int KT = H_DIM / 64;
    for (int kt = 0; kt < KT; ++kt) {
        const int cur = kt & 1, nxt = cur ^ 1;
        if (kt + 1 < KT) {
            #pragma unroll
            for (int i = 0; i < 4; ++i)
                load_lds16(aSrc[i] + (kt + 1) * 64, &sA[nxt][w * 32 + i * 8][0]);
            const float* p0 = b0p + (kt + 1) * 64;
            const float* p1 = b1p + (kt + 1) * 64;
            #pragma unroll
            for (int i = 0; i < 4; ++i) { rb0[i] = *(const f32x4v*)(p0 + i * 4); rb1[i] = *(const f32x4v*)(p1 + i * 4); }
        }
        #pragma unroll
        for (int h = 0; h < 2; ++h) {
            bf16x8 af[4], b0f[4], b1f[4];
            #pragma unroll
            for (int mf = 0; mf < 4; ++mf) {
                int ar = wr * 64 + mf * 16 + frow;
                int c  = (h * 4 + fsel) ^ (ar & 7);
                af[mf] = *(const bf16x8*)((const char*)&sA[cur][0][0] + ar * 128 + c * 16);
            }
            #pragma unroll
            for (int nf = 0; nf < 4; ++nf) {
                int br = wc * 64 + nf * 16 + frow;
                b0f[nf] = *(const bf16x8*)&sB0[cur][br][h * 32 + fsel * 8];
                b1f[nf] = *(const bf16x8*)&sB1[cur][br][h * 32 + fsel * 8];
            }
            #pragma unroll
            for (int nf = 0; nf < 4; ++nf)
                #pragma unroll
                for (int mf = 0; mf < 4; ++mf) {
                    accg[mf][nf] = __builtin_amdgcn_mfma_f32_16x16x32_bf16(af[mf], b0f[nf], accg[mf][nf], 0, 0, 0);
                    accu[mf][nf] = __builtin_amdgcn_mfma_f32_16x16x32_bf16(af[mf], b1f[nf], accu[mf][nf], 0, 0, 0);
                }
        }
        if (kt + 1 < KT) {
            short* d0 = &sB0[nxt][brow][bq * 16];
            *(bf16x8*)d0       = pack8(rb0[0], rb0[1]);
            *(bf16x8*)(d0 + 8) = pack8(rb0[2], rb0[3]);
            short* d1 = &sB1[nxt][brow][bq * 16];
            *(bf16x8*)d1       = pack8(rb1[0], rb1[1]);
            *(bf16x8*)(d1 + 8) = pack8(rb1[2], rb1[3]);
        }
        __syncthreads();
    }

    const int r4 = fsel * 4;
    #pragma unroll
    for (int mf = 0; mf < 4; ++mf)
        #pragma unroll
        for (int nf = 0; nf < 4; ++nf)
            #pragma unroll
            for (int j = 0; j < 4; ++j) {
                int rr = wr * 64 + mf * 16 + r4 + j;
                if (rr < rows) {
                    float g = accg[mf][nf][j];
                    float u = accu[mf][nf][j];
                    float sig = 1.f / (1.f + __expf(-g));
                    float v = g * sig * u * sPw[rr];
                    int col = n0 + wc * 64 + nf * 16 + frow;
                    Hbuf[(size_t)(row0 + rr) * I_DIM + col] = f2bf(v);
                }
            }
}

__global__ __launch_bounds__(256, 2) void gemm2_kernel(
    const short* __restrict__ Hbuf, const float* __restrict__ Wo,
    const int* __restrict__ pair_token,
    const int* __restrict__ tile_expert, const int* __restrict__ tile_row0,
    const int* __restrict__ tile_rows,
    float* __restrict__ out)
{
    const int tile = blockIdx.x;
    const int rows = tile_rows[tile];
    if (rows == 0) return;
    const int e    = tile_expert[tile];
    const int row0 = tile_row0[tile];
    const int n0   = blockIdx.y * 256;

    __shared__ short sA[BM][BK + 8];
    __shared__ short sB[256][BK + 8];
    __shared__ int   sTok[BM];

    const int tid = threadIdx.x;
    if (tid < BM) sTok[tid] = pair_token[row0 + min(tid, rows - 1)];
    __syncthreads();

    const int srow  = tid >> 1;
    const int shalf = tid & 1;

    const short* aptr = Hbuf + (size_t)(row0 + min(srow, rows - 1)) * I_DIM + shalf * 16;
    const float* bptrA = Wo + ((size_t)e * H_DIM + (n0 + srow))       * I_DIM + shalf * 16;
    const float* bptrB = Wo + ((size_t)e * H_DIM + (n0 + srow + 128)) * I_DIM + shalf * 16;

    bf16x8 ra[2];
    f32x4v rbA[4], rbB[4];
    f32x4v acc[4][8];
    #pragma unroll
    for (int mf = 0; mf < 4; ++mf)
        #pragma unroll
        for (int nf = 0; nf < 8; ++nf) acc[mf][nf] = (f32x4v)0.f;

    const int lane = tid & 63;
    const int wid  = tid >> 6;
    const int wr   = wid >> 1;
    const int wc   = wid & 1;
    const int frow = lane & 15;
    const int fk   = (lane >> 4) * 8;

    ra[0] = *(const bf16x8*)(aptr);
    ra[1] = *(const bf16x8*)(aptr + 8);
    #pragma unroll
    for (int i = 0; i < 4; ++i) { rbA[i] = *(const f32x4v*)(bptrA + i * 4); rbB[i] = *(const f32x4v*)(bptrB + i * 4); }

    const int KT = I_DIM / BK;
    for (int kt = 0; kt < KT; ++kt) {
        __syncthreads();
        *(bf16x8*)&sA[srow][shalf * 16]           = ra[0];
        *(bf16x8*)&sA[srow][shalf * 16 + 8]       = ra[1];
        *(bf16x8*)&sB[srow][shalf * 16]           = pack8(rbA[0], rbA[1]);
        *(bf16x8*)&sB[srow][shalf * 16 + 8]       = pack8(rbA[2], rbA[3]);
        *(bf16x8*)&sB[srow + 128][shalf * 16]     = pack8(rbB[0], rbB[1]);
        *(bf16x8*)&sB[srow + 128][shalf * 16 + 8] = pack8(rbB[2], rbB[3]);
        __syncthreads();

        if (kt + 1 < KT) {
            const int k = (kt + 1) * BK;
            ra[0] = *(const bf16x8*)(aptr + k);
            ra[1] = *(const bf16x8*)(aptr + k + 8);
            #pragma unroll
            for (int i = 0; i < 4; ++i) { rbA[i] = *(const f32x4v*)(bptrA + k + i * 4); rbB[i] = *(const f32x4v*)(bptrB + k + i * 4); }
        }

        bf16x8 af[4];
        #pragma unroll
        for (int mf = 0; mf < 4; ++mf)
            af[mf] = *(const bf16x8*)&sA[wr * 64 + mf * 16 + frow][fk];
        #pragma unroll
        for (int nf = 0; nf < 8; ++nf) {
            bf16x8 bfv = *(const bf16x8*)&sB[wc * 128 + nf * 16 + frow][fk];
            #pragma unroll
            for (int mf = 0; mf < 4; ++mf)
                acc[mf][nf] = __builtin_amdgcn_mfma_f32_16x16x32_bf16(af[mf], bfv, acc[mf][nf], 0, 0, 0);
        }
    }

    const int r4 = (lane >> 4) * 4;
    #pragma unroll
    for (int mf = 0; mf < 4; ++mf)
        #pragma unroll
        for (int nf = 0; nf < 8; ++nf)
            #pragma unroll
            for (int j = 0; j < 4; ++j) {
                int rr = wr * 64 + mf * 16 + r4 + j;
                if (rr < rows) {
                    int col = n0 + wc * 128 + nf * 16 + (lane & 15);
                    atomicAdd(out + (size_t)sTok[rr] * H_DIM + col, acc[mf][nf][j]);
                }
            }
}

// ---------------- launch ----------------
extern "C" void kernel_launch(void* const* d_in, const int* in_sizes, int n_in,
                              void* d_out, int out_size, void* d_ws, size_t ws_size,
                              hipStream_t stream)
{
    (void)in_sizes; (void)n_in;
    const float* X     = (const float*)d_in[0];
    const float* topw  = (const float*)d_in[1];
    const int*   topid = (const int*)d_in[2];
    const float* Wi0   = (const float*)d_in[3];
    const float* Wi1   = (const float*)d_in[4];
    const float* Wo    = (const float*)d_in[5];
    float* out = (float*)d_out;

    char* ws = (char*)d_ws;
    int*   pair_token  = (int*)ws;
    float* pair_w      = (float*)(ws + NPAIR * 4);
    int*   tile_expert = (int*)(ws + NPAIR * 8);
    int*   tile_row0   = tile_expert + MAXT;
    int*   tile_rows   = tile_row0 + MAXT;
    int*   t1_expert   = tile_rows + MAXT;
    int*   t1_row0     = t1_expert + MAXT1;
    int*   t1_rows     = t1_row0 + MAXT1;

    route_kernel<<<1, 256, 0, stream>>>(topid, topw, pair_token, pair_w,
                                        tile_expert, tile_row0, tile_rows,
                                        t1_expert, t1_row0, t1_rows);

    if (ws_size >= NEED_NEW) {
        short* Ht  = (short*)(ws + HT_OFF);
        short* At  = (short*)(ws + AT_OFF);
        short* Ws  = (short*)(ws + WS_OFF);
        short* Wot = (short*)(ws + W0_OFF);   // overlays At/Ws (dead after gemm1f)

        aprep128_kernel<<<2304, 256, 0, stream>>>(X, pair_token, tile_row0, tile_rows, At);
        wsprep_kernel<<<8192, 256, 0, stream>>>(Wi0, Wi1, Ws);

        gemm1f_kernel<<<2304, 256, 0, stream>>>(
            At, Ws, pair_w, tile_expert, tile_row0, tile_rows, Ht);

        hipMemsetAsync(d_out, 0, (size_t)out_size * sizeof(float), stream);

        woprep2_kernel<<<4096, 256, 0, stream>>>(Wo, Wot);

        gemm2s_kernel<<<2304, 256, 0, stream>>>(
            Ht, Wot, pair_token, tile_expert, tile_row0, tile_rows, out);
    } else {
        short* Hbuf = (short*)(ws + (1 << 20));
        short* Xbf  = (short*)d_out;

        cvt_kernel<<<T_TOK * H_DIM / (256 * 8), 256, 0, stream>>>(X, Xbf);

        gemm1_kernel<<<dim3(MAXT1, I_DIM / BN1), 512, 0, stream>>>(
            Xbf, Wi0, Wi1, pair_token, pair_w, t1_expert, t1_row0, t1_rows, Hbuf);

        hipMemsetAsync(d_out, 0, (size_t)out_size * sizeof(float), stream);

        gemm2_kernel<<<dim3(MAXT, H_DIM / 256), 256, 0, stream>>>(
            Hbuf, Wo, pair_token, tile_expert, tile_row0, tile_rows, out);
    }
}

// Round 14
// 797.748 us; speedup vs baseline: 1.0384x; 1.0384x over previous
//
#include <hip/hip_runtime.h>
#include <hip/hip_bf16.h>

#define T_TOK 4096
#define H_DIM 4096
#define I_DIM 2048
#define N_EXP 8
#define TOPK  2
#define NPAIR (T_TOK*TOPK)          // 8192
#define BM    128
#define BK    32
#define MAXT  (NPAIR/BM + N_EXP)    // 72
#define BM1   256
#define BN1   128
#define MAXT1 (NPAIR/BM1 + N_EXP)   // 40

// ---- workspace offsets (bytes) ----
#define HT_OFF   ((size_t)1 << 20)                  // Ht128: 37.7MB
#define W0_OFF   ((size_t)44 << 20)                 // Wot128: 134MB (written AFTER gemm1f)
#define AT_OFF   ((size_t)44 << 20)                 // At128: 72MB (dead after gemm1f)
#define WS_OFF   ((size_t)120 << 20)                // Ws paired bf16: 268MB (dead after gemm1f)
#define NEED_NEW (WS_OFF + 268435456ull)            // ~376 MiB

typedef __attribute__((ext_vector_type(8))) short  bf16x8;
typedef __attribute__((ext_vector_type(4))) float  f32x4v;

__device__ __forceinline__ short f2bf(float f) {
    __hip_bfloat16 h = __float2bfloat16(f);
    return __builtin_bit_cast(short, h);
}
__device__ __forceinline__ float bf2f(short s) {
    unsigned int u = ((unsigned int)(unsigned short)s) << 16;
    return __builtin_bit_cast(float, u);
}

__device__ __forceinline__ bf16x8 pack8(f32x4v a, f32x4v b) {
    bf16x8 r;
    r[0]=f2bf(a[0]); r[1]=f2bf(a[1]); r[2]=f2bf(a[2]); r[3]=f2bf(a[3]);
    r[4]=f2bf(b[0]); r[5]=f2bf(b[1]); r[6]=f2bf(b[2]); r[7]=f2bf(b[3]);
    return r;
}

__device__ __forceinline__ void load_lds16(const short* g, short* l) {
    __builtin_amdgcn_global_load_lds(
        (const __attribute__((address_space(1))) void*)g,
        (__attribute__((address_space(3))) void*)l, 16, 0, 0);
}

// ---------------- fp32 -> bf16 plain (fallback X path) ----------------
__global__ void cvt_kernel(const float* __restrict__ X, short* __restrict__ Xbf) {
    const size_t i = ((size_t)blockIdx.x * 256 + threadIdx.x) * 8;
    f32x4v a = *(const f32x4v*)(X + i);
    f32x4v b = *(const f32x4v*)(X + i + 4);
    *(bf16x8*)(Xbf + i) = pack8(a, b);
}

// ---------------- routing ----------------
__global__ void route_kernel(const int* __restrict__ ids, const float* __restrict__ wts,
                             int* __restrict__ pair_token, float* __restrict__ pair_w,
                             int* __restrict__ tile_expert, int* __restrict__ tile_row0,
                             int* __restrict__ tile_rows,
                             int* __restrict__ t1_expert, int* __restrict__ t1_row0,
                             int* __restrict__ t1_rows)
{
    __shared__ int scn[256][N_EXP];
    const int tid = threadIdx.x;
    const int PPT = NPAIR / 256;
    const int base = tid * PPT;

    int c[N_EXP], orig[N_EXP];
    #pragma unroll
    for (int e = 0; e < N_EXP; ++e) c[e] = 0;
    for (int p = 0; p < PPT; ++p) c[ids[base + p]]++;
    #pragma unroll
    for (int e = 0; e < N_EXP; ++e) { orig[e] = c[e]; scn[tid][e] = c[e]; }
    __syncthreads();

    for (int off = 1; off < 256; off <<= 1) {
        int add[N_EXP];
        #pragma unroll
        for (int e = 0; e < N_EXP; ++e) add[e] = (tid >= off) ? scn[tid - off][e] : 0;
        __syncthreads();
        #pragma unroll
        for (int e = 0; e < N_EXP; ++e) { c[e] += add[e]; scn[tid][e] = c[e]; }
        __syncthreads();
    }

    int segs[N_EXP + 1];
    {
        int run = 0;
        #pragma unroll
        for (int e = 0; e < N_EXP; ++e) { segs[e] = run; run += scn[255][e]; }
        segs[N_EXP] = run;
    }
    int pos[N_EXP];
    #pragma unroll
    for (int e = 0; e < N_EXP; ++e) pos[e] = segs[e] + c[e] - orig[e];

    for (int p = 0; p < PPT; ++p) {
        int pp = base + p;
        int e = ids[pp];
        int q = pos[e]++;
        pair_token[q] = pp / TOPK;
        pair_w[q]     = wts[pp];
    }

    if (tid == 0) {
        int t = 0;
        for (int e = 0; e < N_EXP; ++e) {
            int s = segs[e], en = segs[e + 1];
            for (int r = s; r < en; r += BM) {
                tile_expert[t] = e; tile_row0[t] = r; tile_rows[t] = min(BM, en - r); ++t;
            }
        }
        for (; t < MAXT; ++t) { tile_expert[t] = 0; tile_row0[t] = 0; tile_rows[t] = 0; }

        t = 0;
        for (int e = 0; e < N_EXP; ++e) {
            int s = segs[e], en = segs[e + 1];
            for (int r = s; r < en; r += BM1) {
                t1_expert[t] = e; t1_row0[t] = r; t1_rows[t] = min(BM1, en - r); ++t;
            }
        }
        for (; t < MAXT1; ++t) { t1_expert[t] = 0; t1_row0[t] = 0; t1_rows[t] = 0; }
    }
}

// ================= coalesced LDS-transpose preps =================
#define PRP 132

// Paired Wi -> Ws [e][slice 32][kt 64][q 8][panel-row 128][x 8]
//   panel row p: g=p>>6 (64-col group), q=(p>>5)&1 (0=gate/Wi0, 1=up/Wi1), c=p&31
__global__ __launch_bounds__(256) void wsprep_kernel(const float* __restrict__ Wi0,
                                                     const float* __restrict__ Wi1,
                                                     short* __restrict__ Ws) {
    const int bid = blockIdx.x;          // 8 * 32 * 32 = 8192
    const int e   = bid >> 10;
    const int nt  = (bid >> 5) & 31;     // slice
    const int ktg = bid & 31;
    __shared__ short lds[128][PRP];
    const int tid = threadIdx.x;
    #pragma unroll
    for (int it = 0; it < 8; ++it) {
        int r  = it * 16 + (tid >> 4);   // panel row 0..127
        int hc = (tid & 15) * 8;
        int g  = r >> 6;
        int q  = (r >> 5) & 1;
        int c  = r & 31;
        const float* W = q ? Wi1 : Wi0;
        const float* s = W + ((size_t)e * 2048 + nt * 64 + g * 32 + c) * 4096 + ktg * 128 + hc;
        f32x4v a = *(const f32x4v*)s;
        f32x4v b = *(const f32x4v*)(s + 4);
        *(bf16x8*)&lds[r][hc] = pack8(a, b);
    }
    __syncthreads();
    short* dst = Ws + ((size_t)(e * 32 + nt)) * 524288 + (size_t)ktg * 2 * 8192;
    #pragma unroll
    for (int it = 0; it < 8; ++it) {
        int idx = it * 256 + tid;
        int c8  = idx >> 7;
        int r   = idx & 127;
        bf16x8 v = *(const bf16x8*)&lds[r][c8 * 8];
        *(bf16x8*)(dst + (size_t)(c8 >> 3) * 8192 + (c8 & 7) * 1024 + r * 8) = v;
    }
}

// X gather -> At128 [tile 72][kt 64][q 8][r 128][x 8]
__global__ __launch_bounds__(256) void aprep128_kernel(const float* __restrict__ X,
                             const int* __restrict__ pair_token,
                             const int* __restrict__ tile_row0, const int* __restrict__ tile_rows,
                             short* __restrict__ At) {
    const int bid  = blockIdx.x;         // 72 * 32 = 2304
    const int tile = bid >> 5;
    const int ktg  = bid & 31;
    const int rows = tile_rows[tile];
    if (rows == 0) return;
    const int row0 = tile_row0[tile];
    __shared__ short lds[128][PRP];
    const int tid = threadIdx.x;
    #pragma unroll
    for (int it = 0; it < 8; ++it) {
        int r  = it * 16 + (tid >> 4);
        int hc = (tid & 15) * 8;
        int tok = pair_token[row0 + min(r, rows - 1)];
        const float* s = X + (size_t)tok * 4096 + ktg * 128 + hc;
        f32x4v a = *(const f32x4v*)s;
        f32x4v b = *(const f32x4v*)(s + 4);
        *(bf16x8*)&lds[r][hc] = pack8(a, b);
    }
    __syncthreads();
    short* dst = At + (size_t)tile * 524288 + (size_t)ktg * 2 * 8192;
    #pragma unroll
    for (int it = 0; it < 8; ++it) {
        int idx = it * 256 + tid;
        int c8  = idx >> 7;
        int r   = idx & 127;
        bf16x8 v = *(const bf16x8*)&lds[r][c8 * 8];
        *(bf16x8*)(dst + (size_t)(c8 >> 3) * 8192 + (c8 & 7) * 1024 + r * 8) = v;
    }
}

// Wo (E,H,I) fp32 -> Wot128 [e][hb 32][kt 32][q 8][r 128][x 8]
__global__ __launch_bounds__(256) void woprep2_kernel(const float* __restrict__ W, short* __restrict__ Wt) {
    const int bid = blockIdx.x;          // 4096
    const int e   = bid >> 9;
    const int hb  = (bid >> 4) & 31;
    const int ktg = bid & 15;
    __shared__ short lds[128][PRP];
    const int tid = threadIdx.x;
    const float* src0 = W + ((size_t)(e * 4096 + hb * 128)) * 2048 + ktg * 128;
    #pragma unroll
    for (int it = 0; it < 8; ++it) {
        int r  = it * 16 + (tid >> 4);
        int hc = (tid & 15) * 8;
        const float* s = src0 + (size_t)r * 2048 + hc;
        f32x4v a = *(const f32x4v*)s;
        f32x4v b = *(const f32x4v*)(s + 4);
        *(bf16x8*)&lds[r][hc] = pack8(a, b);
    }
    __syncthreads();
    short* dst = Wt + ((size_t)(e * 32 + hb)) * 262144 + (size_t)ktg * 2 * 8192;
    #pragma unroll
    for (int it = 0; it < 8; ++it) {
        int idx = it * 256 + tid;
        int c8  = idx >> 7;
        int r   = idx & 127;
        bf16x8 v = *(const bf16x8*)&lds[r][c8 * 8];
        *(bf16x8*)(dst + (size_t)(c8 >> 3) * 8192 + (c8 & 7) * 1024 + r * 8) = v;
    }
}

// ================= GEMM1f: fused gate/up + silu, 128x128 tile, BK=64, 64x64 wave quadrants =================
// SLICE-MAJOR XCD mapping: concurrent blocks on an XCD = adjacent tiles (mostly same expert)
// at the SAME slice -> B-panel L2-shared; A-tile re-reads absorbed by L3 (At=72MB resident).
__global__ __launch_bounds__(256, 3) void gemm1f_kernel(
    const short* __restrict__ At,       // [72][64][8][128][8]
    const short* __restrict__ Ws,       // [E][32][64][8][128 paired][8]
    const float* __restrict__ pair_w,
    const int* __restrict__ tile_expert, const int* __restrict__ tile_row0,
    const int* __restrict__ tile_rows,
    short* __restrict__ Ht)             // [72][32][8][128][8]
{
    const int b   = blockIdx.x;          // 2304 = 72*32
    const int xcd = b & 7;
    const int i   = b >> 3;              // 0..287
    const int tile  = xcd * 9 + (i % 9);     // 9 tiles per XCD
    const int n0idx = i / 9;                 // slice 0..31
    const int rows = tile_rows[tile];
    if (rows == 0) return;
    const int e    = tile_expert[tile];
    const int row0 = tile_row0[tile];

    __shared__ short sAB[2048 * 8];      // 32 KB
    __shared__ float sPw[128];

    const int tid  = threadIdx.x;
    const int lane = tid & 63;
    const int w    = tid >> 6;

    if (tid < 128) sPw[tid] = (tid < rows) ? pair_w[row0 + tid] : 0.f;
    __syncthreads();

    const short* aT = At + (size_t)tile * 524288;
    const short* bT = Ws + ((size_t)e * 32 + n0idx) * 524288;

    const int wr = w >> 1, wc = w & 1;
    const int frow = lane & 15, fsel = lane >> 4;

    f32x4v acc[4][4];
    #pragma unroll
    for (int mf = 0; mf < 4; ++mf)
        #pragma unroll
        for (int nf = 0; nf < 4; ++nf) acc[mf][nf] = (f32x4v)0.f;

    const int KT = H_DIM / 64;           // 64
    for (int kt = 0; kt < KT; ++kt) {
        __syncthreads();
        {
            const size_t ko = (size_t)kt * 8192;
            #pragma unroll
            for (int i2 = 0; i2 < 4; ++i2) {
                load_lds16(aT + ko + (size_t)tid * 8 + i2 * 2048,
                           &sAB[(i2 * 256 + w * 64) * 8]);
                load_lds16(bT + ko + (size_t)tid * 8 + i2 * 2048,
                           &sAB[((1024 + i2 * 256 + w * 64)) * 8]);
            }
        }
        __syncthreads();

        #pragma unroll
        for (int h = 0; h < 2; ++h) {
            const int c = h * 4 + fsel;
            bf16x8 af[4];
            #pragma unroll
            for (int mf = 0; mf < 4; ++mf)
                af[mf] = *(const bf16x8*)&sAB[(c * 128 + wr * 64 + mf * 16 + frow) * 8];
            #pragma unroll
            for (int nf = 0; nf < 4; ++nf) {
                bf16x8 bf = *(const bf16x8*)&sAB[(1024 + c * 128 + wc * 64 + nf * 16 + frow) * 8];
                #pragma unroll
                for (int mf = 0; mf < 4; ++mf)
                    acc[mf][nf] = __builtin_amdgcn_mfma_f32_16x16x32_bf16(af[mf], bf, acc[mf][nf], 0, 0, 0);
            }
        }
    }

    // fused epilogue: gate=acc[mf][nfg], up=acc[mf][nfg+2] -> silu*pw -> Ht
    #pragma unroll
    for (int mf = 0; mf < 4; ++mf)
        #pragma unroll
        for (int nfg = 0; nfg < 2; ++nfg) {
            const int c_g = n0idx * 64 + wc * 32 + nfg * 16 + frow;   // I-col
            const size_t cb = (size_t)tile * 262144 + (size_t)(c_g >> 6) * 8192
                            + ((c_g >> 3) & 7) * 1024 + (c_g & 7);
            #pragma unroll
            for (int j = 0; j < 4; ++j) {
                int row = wr * 64 + mf * 16 + fsel * 4 + j;
                if (row < rows) {
                    float g = acc[mf][nfg][j];
                    float u = acc[mf][nfg + 2][j];
                    float sig = 1.f / (1.f + __expf(-g));
                    Ht[cb + (size_t)row * 8] = f2bf(g * sig * u * sPw[row]);
                }
            }
        }
}

// ================= GEMM2s: 128x128 tile, BK=64, m97 shape (control, unchanged) =================
__global__ __launch_bounds__(256, 3) void gemm2s_kernel(
    const short* __restrict__ Ht,       // [72][32][8][128][8]
    const short* __restrict__ Wot,      // [E][32][32][8][128][8]
    const int* __restrict__ pair_token,
    const int* __restrict__ tile_expert, const int* __restrict__ tile_row0,
    const int* __restrict__ tile_rows,
    float* __restrict__ out)            // [T][H]
{
    const int b   = blockIdx.x;          // 2304 = 72*32
    const int l   = (b & 7) * 288 + (b >> 3);
    const int tile  = l >> 5;
    const int n0idx = l & 31;            // over H/128
    const int rows = tile_rows[tile];
    if (rows == 0) return;
    const int e    = tile_expert[tile];
    const int row0 = tile_row0[tile];

    __shared__ short sAB[2048 * 8];      // 32 KB
    __shared__ int   sTok[128];

    const int tid  = threadIdx.x;
    const int lane = tid & 63;
    const int w    = tid >> 6;

    if (tid < 128) sTok[tid] = pair_token[row0 + min(tid, rows - 1)];
    __syncthreads();

    const short* aT = Ht  + (size_t)tile * 262144;
    const short* bT = Wot + ((size_t)e * 32 + n0idx) * 262144;

    const int wr = w >> 1, wc = w & 1;
    const int frow = lane & 15, fsel = lane >> 4;

    f32x4v acc[4][4];
    #pragma unroll
    for (int mf = 0; mf < 4; ++mf)
        #pragma unroll
        for (int nf = 0; nf < 4; ++nf) acc[mf][nf] = (f32x4v)0.f;

    const int KT = I_DIM / 64;           // 32
    for (int kt = 0; kt < KT; ++kt) {
        __syncthreads();
        {
            const size_t ko = (size_t)kt * 8192;
            #pragma unroll
            for (int i2 = 0; i2 < 4; ++i2) {
                load_lds16(aT + ko + (size_t)tid * 8 + i2 * 2048,
                           &sAB[(i2 * 256 + w * 64) * 8]);
                load_lds16(bT + ko + (size_t)tid * 8 + i2 * 2048,
                           &sAB[((1024 + i2 * 256 + w * 64)) * 8]);
            }
        }
        __syncthreads();

        #pragma unroll
        for (int h = 0; h < 2; ++h) {
            const int c = h * 4 + fsel;
            bf16x8 af[4];
            #pragma unroll
            for (int mf = 0; mf < 4; ++mf)
                af[mf] = *(const bf16x8*)&sAB[(c * 128 + wr * 64 + mf * 16 + frow) * 8];
            #pragma unroll
            for (int nf = 0; nf < 4; ++nf) {
                bf16x8 bf = *(const bf16x8*)&sAB[(1024 + c * 128 + wc * 64 + nf * 16 + frow) * 8];
                #pragma unroll
                for (int mf = 0; mf < 4; ++mf)
                    acc[mf][nf] = __builtin_amdgcn_mfma_f32_16x16x32_bf16(af[mf], bf, acc[mf][nf], 0, 0, 0);
            }
        }
    }

    const int r4 = fsel * 4;
    #pragma unroll
    for (int mf = 0; mf < 4; ++mf)
        #pragma unroll
        for (int nf = 0; nf < 4; ++nf) {
            const int col = n0idx * 128 + wc * 64 + nf * 16 + frow;
            #pragma unroll
            for (int j = 0; j < 4; ++j) {
                int rr = wr * 64 + mf * 16 + r4 + j;
                if (rr < rows)
                    atomicAdd(out + (size_t)sTok[rr] * H_DIM + col, acc[mf][nf][j]);
            }
        }
}

// ================= FALLBACK PATH (R3) =================
__global__ __launch_bounds__(512, 2) void gemm1_kernel(
    const short* __restrict__ Xbf, const float* __restrict__ Wi0, const float* __restrict__ Wi1,
    const int* __restrict__ pair_token, const float* __restrict__ pair_w,
    const int* __restrict__ t1_expert, const int* __restrict__ t1_row0, const int* __restrict__ t1_rows,
    short* __restrict__ Hbuf)
{
    const int tile = blockIdx.x;
    const int rows = t1_rows[tile];
    if (rows == 0) return;
    const int e    = t1_expert[tile];
    const int row0 = t1_row0[tile];
    const int n0   = blockIdx.y * BN1;

    __shared__ short sA [2][BM1][64];
    __shared__ short sB0[2][BN1][64 + 8];
    __shared__ short sB1[2][BN1][64 + 8];
    __shared__ int   sTok[BM1];
    __shared__ float sPw [BM1];

    const int tid  = threadIdx.x;
    const int lane = tid & 63;
    const int w    = tid >> 6;

    if (tid < BM1) {
        int tr = min(tid, rows - 1);
        sTok[tid] = pair_token[row0 + tr];
        sPw[tid]  = (tid < rows) ? pair_w[row0 + tid] : 0.f;
    }
    __syncthreads();

    const short* aSrc[4];
    #pragma unroll
    for (int i = 0; i < 4; ++i) {
        int r = w * 32 + i * 8 + (lane >> 3);
        int j = lane & 7;
        aSrc[i] = Xbf + (size_t)sTok[r] * H_DIM + ((j ^ (r & 7)) * 8);
    }

    const int brow = tid >> 2;
    const int bq   = tid & 3;
    const size_t wboff = ((size_t)e * I_DIM + (n0 + brow)) * H_DIM + bq * 16;
    const float* b0p = Wi0 + wboff;
    const float* b1p = Wi1 + wboff;

    const int wr   = w >> 1;
    const int wc   = w & 1;
    const int frow = lane & 15;
    const int fsel = lane >> 4;

    f32x4v accg[4][4], accu[4][4];
    #pragma unroll
    for (int mf = 0; mf < 4; ++mf)
        #pragma unroll
        for (int nf = 0; nf < 4; ++nf) { accg[mf][nf] = (f32x4v)0.f; accu[mf][nf] = (f32x4v)0.f; }

    f32x4v rb0[4], rb1[4];

    #pragma unroll
    for (int i = 0; i < 4; ++i)
        load_lds16(aSrc[i], &sA[0][w * 32 + i * 8][0]);
    #pragma unroll
    for (int i = 0; i < 4; ++i) { rb0[i] = *(const f32x4v*)(b0p + i * 4); rb1[i] = *(const f32x4v*)(b1p + i * 4); }
    {
        short* d0 = &sB0[0][brow][bq * 16];
        *(bf16x8*)d0       = pack8(rb0[0], rb0[1]);
        *(bf16x8*)(d0 + 8) = pack8(rb0[2], rb0[3]);
        short* d1 = &sB1[0][brow][bq * 16];
        *(bf16x8*)d1       = pack8(rb1[0], rb1[1]);
        *(bf16x8*)(d1 + 8) = pack8(rb1[2], rb1[3]);
    }
    __syncthreads();

    const int KT = H_DIM / 64;
    for (int kt = 0; kt < KT; ++kt) {
        const int cur = kt & 1, nxt = cur ^ 1;
        if (kt + 1 < KT) {
            #pragma unroll
            for (int i = 0; i < 4; ++i)
                load_lds16(aSrc[i] + (kt + 1) * 64, &sA[nxt][w * 32 + i * 8][0]);
            const float* p0 = b0p + (kt + 1) * 64;
            const float* p1 = b1p + (kt + 1) * 64;
            #pragma unroll
            for (int i = 0; i < 4; ++i) { rb0[i] = *(const f32x4v*)(p0 + i * 4); rb1[i] = *(const f32x4v*)(p1 + i * 4); }
        }
        #pragma unroll
        for (int h = 0; h < 2; ++h) {
            bf16x8 af[4], b0f[4], b1f[4];
            #pragma unroll
            for (int mf = 0; mf < 4; ++mf) {
                int ar = wr * 64 + mf * 16 + frow;
                int c  = (h * 4 + fsel) ^ (ar & 7);
                af[mf] = *(const bf16x8*)((const char*)&sA[cur][0][0] + ar * 128 + c * 16);
            }
            #pragma unroll
            for (int nf = 0; nf < 4; ++nf) {
                int br = wc * 64 + nf * 16 + frow;
                b0f[nf] = *(const bf16x8*)&sB0[cur][br][h * 32 + fsel * 8];
                b1f[nf] = *(const bf16x8*)&sB1[cur][br][h * 32 + fsel * 8];
            }
            #pragma unroll
            for (int nf = 0; nf < 4; ++nf)
                #pragma unroll
                for (int mf = 0; mf < 4; ++mf) {
                    accg[mf][nf] = __builtin_amdgcn_mfma_f32_16x16x32_bf16(af[mf], b0f[nf], accg[mf][nf], 0, 0, 0);
                    accu[mf][nf] = __builtin_amdgcn_mfma_f32_16x16x32_bf16(af[mf], b1f[nf], accu[mf][nf], 0, 0, 0);
                }
        }
        if (kt + 1 < KT) {
            short* d0 = &sB0[nxt][brow][bq * 16];
            *(bf16x8*)d0       = pack8(rb0[0], rb0[1]);
            *(bf16x8*)(d0 + 8) = pack8(rb0[2], rb0[3]);
            short* d1 = &sB1[nxt][brow][bq * 16];
            *(bf16x8*)d1       = pack8(rb1[0], rb1[1]);
            *(bf16x8*)(d1 + 8) = pack8(rb1[2], rb1[3]);
        }
        __syncthreads();
    }

    const int r4 = fsel * 4;
    #pragma unroll
    for (int mf = 0; mf < 4; ++mf)
        #pragma unroll
        for (int nf = 0; nf < 4; ++nf)
            #pragma unroll
            for (int j = 0; j < 4; ++j) {
                int rr = wr * 64 + mf * 16 + r4 + j;
                if (rr < rows) {
                    float g = accg[mf][nf][j];
                    float u = accu[mf][nf][j];
                    float sig = 1.f / (1.f + __expf(-g));
                    float v = g * sig * u * sPw[rr];
                    int col = n0 + wc * 64 + nf * 16 + frow;
                    Hbuf[(size_t)(row0 + rr) * I_DIM + col] = f2bf(v);
                }
            }
}

__global__ __launch_bounds__(256, 2) void gemm2_kernel(
    const short* __restrict__ Hbuf, const float* __restrict__ Wo,
    const int* __restrict__ pair_token,
    const int* __restrict__ tile_expert, const int* __restrict__ tile_row0,
    const int* __restrict__ tile_rows,
    float* __restrict__ out)
{
    const int tile = blockIdx.x;
    const int rows = tile_rows[tile];
    if (rows == 0) return;
    const int e    = tile_expert[tile];
    const int row0 = tile_row0[tile];
    const int n0   = blockIdx.y * 256;

    __shared__ short sA[BM][BK + 8];
    __shared__ short sB[256][BK + 8];
    __shared__ int   sTok[BM];

    const int tid = threadIdx.x;
    if (tid < BM) sTok[tid] = pair_token[row0 + min(tid, rows - 1)];
    __syncthreads();

    const int srow  = tid >> 1;
    const int shalf = tid & 1;

    const short* aptr = Hbuf + (size_t)(row0 + min(srow, rows - 1)) * I_DIM + shalf * 16;
    const float* bptrA = Wo + ((size_t)e * H_DIM + (n0 + srow))       * I_DIM + shalf * 16;
    const float* bptrB = Wo + ((size_t)e * H_DIM + (n0 + srow + 128)) * I_DIM + shalf * 16;

    bf16x8 ra[2];
    f32x4v rbA[4], rbB[4];
    f32x4v acc[4][8];
    #pragma unroll
    for (int mf = 0; mf < 4; ++mf)
        #pragma unroll
        for (int nf = 0; nf < 8; ++nf) acc[mf][nf] = (f32x4v)0.f;

    const int lane = tid & 63;
    const int wid  = tid >> 6;
    const int wr   = wid >> 1;
    const int wc   = wid & 1;
    const int frow = lane & 15;
    const int fk   = (lane >> 4) * 8;

    ra[0] = *(const bf16x8*)(aptr);
    ra[1] = *(const bf16x8*)(aptr + 8);
    #pragma unroll
    for (int i = 0; i < 4; ++i) { rbA[i] = *(const f32x4v*)(bptrA + i * 4); rbB[i] = *(const f32x4v*)(bptrB + i * 4); }

    const int KT = I_DIM / BK;
    for (int kt = 0; kt < KT; ++kt) {
        __syncthreads();
        *(bf16x8*)&sA[srow][shalf * 16]           = ra[0];
        *(bf16x8*)&sA[srow][shalf * 16 + 8]       = ra[1];
        *(bf16x8*)&sB[srow][shalf * 16]           = pack8(rbA[0], rbA[1]);
        *(bf16x8*)&sB[srow][shalf * 16 + 8]       = pack8(rbA[2], rbA[3]);
        *(bf16x8*)&sB[srow + 128][shalf * 16]     = pack8(rbB[0], rbB[1]);
        *(bf16x8*)&sB[srow + 128][shalf * 16 + 8] = pack8(rbB[2], rbB[3]);
        __syncthreads();

        if (kt + 1 < KT) {
            const int k = (kt + 1) * BK;
            ra[0] = *(const bf16x8*)(aptr + k);
            ra[1] = *(const bf16x8*)(aptr + k + 8);
            #pragma unroll
            for (int i = 0; i < 4; ++i) { rbA[i] = *(const f32x4v*)(bptrA + k + i * 4); rbB[i] = *(const f32x4v*)(bptrB + k + i * 4); }
        }

        bf16x8 af[4];
        #pragma unroll
        for (int mf = 0; mf < 4; ++mf)
            af[mf] = *(const bf16x8*)&sA[wr * 64 + mf * 16 + frow][fk];
        #pragma unroll
        for (int nf = 0; nf < 8; ++nf) {
            bf16x8 bfv = *(const bf16x8*)&sB[wc * 128 + nf * 16 + frow][fk];
            #pragma unroll
            for (int mf = 0; mf < 4; ++mf)
                acc[mf][nf] = __builtin_amdgcn_mfma_f32_16x16x32_bf16(af[mf], bfv, acc[mf][nf], 0, 0, 0);
        }
    }

    const int r4 = (lane >> 4) * 4;
    #pragma unroll
    for (int mf = 0; mf < 4; ++mf)
        #pragma unroll
        for (int nf = 0; nf < 8; ++nf)
            #pragma unroll
            for (int j = 0; j < 4; ++j) {
                int rr = wr * 64 + mf * 16 + r4 + j;
                if (rr < rows) {
                    int col = n0 + wc * 128 + nf * 16 + (lane & 15);
                    atomicAdd(out + (size_t)sTok[rr] * H_DIM + col, acc[mf][nf][j]);
                }
            }
}

// ---------------- launch ----------------
extern "C" void kernel_launch(void* const* d_in, const int* in_sizes, int n_in,
                              void* d_out, int out_size, void* d_ws, size_t ws_size,
                              hipStream_t stream)
{
    (void)in_sizes; (void)n_in;
    const float* X     = (const float*)d_in[0];
    const float* topw  = (const float*)d_in[1];
    const int*   topid = (const int*)d_in[2];
    const float* Wi0   = (const float*)d_in[3];
    const float* Wi1   = (const float*)d_in[4];
    const float* Wo    = (const float*)d_in[5];
    float* out = (float*)d_out;

    char* ws = (char*)d_ws;
    int*   pair_token  = (int*)ws;
    float* pair_w      = (float*)(ws + NPAIR * 4);
    int*   tile_expert = (int*)(ws + NPAIR * 8);
    int*   tile_row0   = tile_expert + MAXT;
    int*   tile_rows   = tile_row0 + MAXT;
    int*   t1_expert   = tile_rows + MAXT;
    int*   t1_row0     = t1_expert + MAXT1;
    int*   t1_rows     = t1_row0 + MAXT1;

    route_kernel<<<1, 256, 0, stream>>>(topid, topw, pair_token, pair_w,
                                        tile_expert, tile_row0, tile_rows,
                                        t1_expert, t1_row0, t1_rows);

    if (ws_size >= NEED_NEW) {
        short* Ht  = (short*)(ws + HT_OFF);
        short* At  = (short*)(ws + AT_OFF);
        short* Ws  = (short*)(ws + WS_OFF);
        short* Wot = (short*)(ws + W0_OFF);   // overlays At/Ws (dead after gemm1f)

        aprep128_kernel<<<2304, 256, 0, stream>>>(X, pair_token, tile_row0, tile_rows, At);
        wsprep_kernel<<<8192, 256, 0, stream>>>(Wi0, Wi1, Ws);

        gemm1f_kernel<<<2304, 256, 0, stream>>>(
            At, Ws, pair_w, tile_expert, tile_row0, tile_rows, Ht);

        hipMemsetAsync(d_out, 0, (size_t)out_size * sizeof(float), stream);

        woprep2_kernel<<<4096, 256, 0, stream>>>(Wo, Wot);

        gemm2s_kernel<<<2304, 256, 0, stream>>>(
            Ht, Wot, pair_token, tile_expert, tile_row0, tile_rows, out);
    } else {
        short* Hbuf = (short*)(ws + (1 << 20));
        short* Xbf  = (short*)d_out;

        cvt_kernel<<<T_TOK * H_DIM / (256 * 8), 256, 0, stream>>>(X, Xbf);

        gemm1_kernel<<<dim3(MAXT1, I_DIM / BN1), 512, 0, stream>>>(
            Xbf, Wi0, Wi1, pair_token, pair_w, t1_expert, t1_row0, t1_rows, Hbuf);

        hipMemsetAsync(d_out, 0, (size_t)out_size * sizeof(float), stream);

        gemm2_kernel<<<dim3(MAXT, H_DIM / 256), 256, 0, stream>>>(
            Hbuf, Wo, pair_token, tile_expert, tile_row0, tile_rows, out);
    }
}

// Round 15
// 795.090 us; speedup vs baseline: 1.0419x; 1.0033x over previous
//
#include <hip/hip_runtime.h>
#include <hip/hip_bf16.h>

#define T_TOK 4096
#define H_DIM 4096
#define I_DIM 2048
#define N_EXP 8
#define TOPK  2
#define NPAIR (T_TOK*TOPK)          // 8192
#define BM    128
#define BK    32
#define MAXT  (NPAIR/BM + N_EXP)    // 72
#define BM1   256
#define BN1   128
#define MAXT1 (NPAIR/BM1 + N_EXP)   // 40

// ---- workspace offsets (bytes) ----
#define HT_OFF   ((size_t)1 << 20)                  // Ht128: 37.7MB
#define W0_OFF   ((size_t)44 << 20)                 // Wot128: 134MB (written AFTER gemm1f)
#define AT_OFF   ((size_t)44 << 20)                 // At128: 72MB (dead after gemm1f)
#define WS_OFF   ((size_t)120 << 20)                // Ws paired bf16: 268MB (dead after gemm1f)
#define NEED_NEW (WS_OFF + 268435456ull)            // ~376 MiB

typedef __attribute__((ext_vector_type(8))) short  bf16x8;
typedef __attribute__((ext_vector_type(4))) float  f32x4v;

__device__ __forceinline__ short f2bf(float f) {
    __hip_bfloat16 h = __float2bfloat16(f);
    return __builtin_bit_cast(short, h);
}
__device__ __forceinline__ float bf2f(short s) {
    unsigned int u = ((unsigned int)(unsigned short)s) << 16;
    return __builtin_bit_cast(float, u);
}

__device__ __forceinline__ bf16x8 pack8(f32x4v a, f32x4v b) {
    bf16x8 r;
    r[0]=f2bf(a[0]); r[1]=f2bf(a[1]); r[2]=f2bf(a[2]); r[3]=f2bf(a[3]);
    r[4]=f2bf(b[0]); r[5]=f2bf(b[1]); r[6]=f2bf(b[2]); r[7]=f2bf(b[3]);
    return r;
}

__device__ __forceinline__ void load_lds16(const short* g, short* l) {
    __builtin_amdgcn_global_load_lds(
        (const __attribute__((address_space(1))) void*)g,
        (__attribute__((address_space(3))) void*)l, 16, 0, 0);
}

// ---------------- fp32 -> bf16 plain (fallback X path) ----------------
__global__ void cvt_kernel(const float* __restrict__ X, short* __restrict__ Xbf) {
    const size_t i = ((size_t)blockIdx.x * 256 + threadIdx.x) * 8;
    f32x4v a = *(const f32x4v*)(X + i);
    f32x4v b = *(const f32x4v*)(X + i + 4);
    *(bf16x8*)(Xbf + i) = pack8(a, b);
}

// ---------------- routing ----------------
__global__ void route_kernel(const int* __restrict__ ids, const float* __restrict__ wts,
                             int* __restrict__ pair_token, float* __restrict__ pair_w,
                             int* __restrict__ tile_expert, int* __restrict__ tile_row0,
                             int* __restrict__ tile_rows,
                             int* __restrict__ t1_expert, int* __restrict__ t1_row0,
                             int* __restrict__ t1_rows)
{
    __shared__ int scn[256][N_EXP];
    const int tid = threadIdx.x;
    const int PPT = NPAIR / 256;
    const int base = tid * PPT;

    int c[N_EXP], orig[N_EXP];
    #pragma unroll
    for (int e = 0; e < N_EXP; ++e) c[e] = 0;
    for (int p = 0; p < PPT; ++p) c[ids[base + p]]++;
    #pragma unroll
    for (int e = 0; e < N_EXP; ++e) { orig[e] = c[e]; scn[tid][e] = c[e]; }
    __syncthreads();

    for (int off = 1; off < 256; off <<= 1) {
        int add[N_EXP];
        #pragma unroll
        for (int e = 0; e < N_EXP; ++e) add[e] = (tid >= off) ? scn[tid - off][e] : 0;
        __syncthreads();
        #pragma unroll
        for (int e = 0; e < N_EXP; ++e) { c[e] += add[e]; scn[tid][e] = c[e]; }
        __syncthreads();
    }

    int segs[N_EXP + 1];
    {
        int run = 0;
        #pragma unroll
        for (int e = 0; e < N_EXP; ++e) { segs[e] = run; run += scn[255][e]; }
        segs[N_EXP] = run;
    }
    int pos[N_EXP];
    #pragma unroll
    for (int e = 0; e < N_EXP; ++e) pos[e] = segs[e] + c[e] - orig[e];

    for (int p = 0; p < PPT; ++p) {
        int pp = base + p;
        int e = ids[pp];
        int q = pos[e]++;
        pair_token[q] = pp / TOPK;
        pair_w[q]     = wts[pp];
    }

    if (tid == 0) {
        int t = 0;
        for (int e = 0; e < N_EXP; ++e) {
            int s = segs[e], en = segs[e + 1];
            for (int r = s; r < en; r += BM) {
                tile_expert[t] = e; tile_row0[t] = r; tile_rows[t] = min(BM, en - r); ++t;
            }
        }
        for (; t < MAXT; ++t) { tile_expert[t] = 0; tile_row0[t] = 0; tile_rows[t] = 0; }

        t = 0;
        for (int e = 0; e < N_EXP; ++e) {
            int s = segs[e], en = segs[e + 1];
            for (int r = s; r < en; r += BM1) {
                t1_expert[t] = e; t1_row0[t] = r; t1_rows[t] = min(BM1, en - r); ++t;
            }
        }
        for (; t < MAXT1; ++t) { t1_expert[t] = 0; t1_row0[t] = 0; t1_rows[t] = 0; }
    }
}

// ================= merged prep: aprep (first 2304 blocks) + wsprep (next 8192) =================
#define PRP 132

__global__ __launch_bounds__(256) void prep12_kernel(
    const float* __restrict__ X,
    const int* __restrict__ pair_token,
    const int* __restrict__ tile_row0, const int* __restrict__ tile_rows,
    short* __restrict__ At,
    const float* __restrict__ Wi0, const float* __restrict__ Wi1,
    short* __restrict__ Ws)
{
    __shared__ short lds[128][PRP];
    const int tid = threadIdx.x;

    if (blockIdx.x < 2304) {
        // ---- aprep: X gather -> At128 [tile 72][kt 64][q 8][r 128][x 8] ----
        const int bid  = blockIdx.x;
        const int tile = bid >> 5;
        const int ktg  = bid & 31;
        const int rows = tile_rows[tile];
        if (rows == 0) return;
        const int row0 = tile_row0[tile];
        #pragma unroll
        for (int it = 0; it < 8; ++it) {
            int r  = it * 16 + (tid >> 4);
            int hc = (tid & 15) * 8;
            int tok = pair_token[row0 + min(r, rows - 1)];
            const float* s = X + (size_t)tok * 4096 + ktg * 128 + hc;
            f32x4v a = *(const f32x4v*)s;
            f32x4v b = *(const f32x4v*)(s + 4);
            *(bf16x8*)&lds[r][hc] = pack8(a, b);
        }
        __syncthreads();
        short* dst = At + (size_t)tile * 524288 + (size_t)ktg * 2 * 8192;
        #pragma unroll
        for (int it = 0; it < 8; ++it) {
            int idx = it * 256 + tid;
            int c8  = idx >> 7;
            int r   = idx & 127;
            bf16x8 v = *(const bf16x8*)&lds[r][c8 * 8];
            *(bf16x8*)(dst + (size_t)(c8 >> 3) * 8192 + (c8 & 7) * 1024 + r * 8) = v;
        }
    } else {
        // ---- wsprep: paired Wi -> Ws [e][slice 32][kt 64][q 8][panel-row 128][x 8]
        //   panel row p: g=p>>6, q=(p>>5)&1 (0=gate,1=up), c=p&31
        const int bid = blockIdx.x - 2304;   // 0..8191
        const int e   = bid >> 10;
        const int nt  = (bid >> 5) & 31;
        const int ktg = bid & 31;
        #pragma unroll
        for (int it = 0; it < 8; ++it) {
            int r  = it * 16 + (tid >> 4);
            int hc = (tid & 15) * 8;
            int g  = r >> 6;
            int q  = (r >> 5) & 1;
            int c  = r & 31;
            const float* W = q ? Wi1 : Wi0;
            const float* s = W + ((size_t)e * 2048 + nt * 64 + g * 32 + c) * 4096 + ktg * 128 + hc;
            f32x4v a = *(const f32x4v*)s;
            f32x4v b = *(const f32x4v*)(s + 4);
            *(bf16x8*)&lds[r][hc] = pack8(a, b);
        }
        __syncthreads();
        short* dst = Ws + ((size_t)(e * 32 + nt)) * 524288 + (size_t)ktg * 2 * 8192;
        #pragma unroll
        for (int it = 0; it < 8; ++it) {
            int idx = it * 256 + tid;
            int c8  = idx >> 7;
            int r   = idx & 127;
            bf16x8 v = *(const bf16x8*)&lds[r][c8 * 8];
            *(bf16x8*)(dst + (size_t)(c8 >> 3) * 8192 + (c8 & 7) * 1024 + r * 8) = v;
        }
    }
}

// Wo (E,H,I) fp32 -> Wot128 [e][hb 32][kt 32][q 8][r 128][x 8]
__global__ __launch_bounds__(256) void woprep2_kernel(const float* __restrict__ W, short* __restrict__ Wt) {
    const int bid = blockIdx.x;          // 4096
    const int e   = bid >> 9;
    const int hb  = (bid >> 4) & 31;
    const int ktg = bid & 15;
    __shared__ short lds[128][PRP];
    const int tid = threadIdx.x;
    const float* src0 = W + ((size_t)(e * 4096 + hb * 128)) * 2048 + ktg * 128;
    #pragma unroll
    for (int it = 0; it < 8; ++it) {
        int r  = it * 16 + (tid >> 4);
        int hc = (tid & 15) * 8;
        const float* s = src0 + (size_t)r * 2048 + hc;
        f32x4v a = *(const f32x4v*)s;
        f32x4v b = *(const f32x4v*)(s + 4);
        *(bf16x8*)&lds[r][hc] = pack8(a, b);
    }
    __syncthreads();
    short* dst = Wt + ((size_t)(e * 32 + hb)) * 262144 + (size_t)ktg * 2 * 8192;
    #pragma unroll
    for (int it = 0; it < 8; ++it) {
        int idx = it * 256 + tid;
        int c8  = idx >> 7;
        int r   = idx & 127;
        bf16x8 v = *(const bf16x8*)&lds[r][c8 * 8];
        *(bf16x8*)(dst + (size_t)(c8 >> 3) * 8192 + (c8 & 7) * 1024 + r * 8) = v;
    }
}

// ================= GEMM1f: fused gate/up + silu, 128x128 tile, BK=64, 64x64 wave quadrants =================
// SLICE-MAJOR XCD mapping (R14-proven): concurrent blocks on an XCD = adjacent tiles at the
// SAME slice -> B-panel L2-shared; A-tile re-reads absorbed by L3.
__global__ __launch_bounds__(256, 4) void gemm1f_kernel(
    const short* __restrict__ At,       // [72][64][8][128][8]
    const short* __restrict__ Ws,       // [E][32][64][8][128 paired][8]
    const float* __restrict__ pair_w,
    const int* __restrict__ tile_expert, const int* __restrict__ tile_row0,
    const int* __restrict__ tile_rows,
    short* __restrict__ Ht)             // [72][32][8][128][8]
{
    const int b   = blockIdx.x;          // 2304 = 72*32
    const int xcd = b & 7;
    const int i   = b >> 3;              // 0..287
    const int tile  = xcd * 9 + (i % 9);     // 9 tiles per XCD
    const int n0idx = i / 9;                 // slice 0..31
    const int rows = tile_rows[tile];
    if (rows == 0) return;
    const int e    = tile_expert[tile];
    const int row0 = tile_row0[tile];

    __shared__ short sAB[2048 * 8];      // 32 KB
    __shared__ float sPw[128];

    const int tid  = threadIdx.x;
    const int lane = tid & 63;
    const int w    = tid >> 6;

    if (tid < 128) sPw[tid] = (tid < rows) ? pair_w[row0 + tid] : 0.f;
    __syncthreads();

    const short* aT = At + (size_t)tile * 524288;
    const short* bT = Ws + ((size_t)e * 32 + n0idx) * 524288;

    const int wr = w >> 1, wc = w & 1;
    const int frow = lane & 15, fsel = lane >> 4;

    f32x4v acc[4][4];
    #pragma unroll
    for (int mf = 0; mf < 4; ++mf)
        #pragma unroll
        for (int nf = 0; nf < 4; ++nf) acc[mf][nf] = (f32x4v)0.f;

    const int KT = H_DIM / 64;           // 64
    for (int kt = 0; kt < KT; ++kt) {
        __syncthreads();
        {
            const size_t ko = (size_t)kt * 8192;
            #pragma unroll
            for (int i2 = 0; i2 < 4; ++i2) {
                load_lds16(aT + ko + (size_t)tid * 8 + i2 * 2048,
                           &sAB[(i2 * 256 + w * 64) * 8]);
                load_lds16(bT + ko + (size_t)tid * 8 + i2 * 2048,
                           &sAB[((1024 + i2 * 256 + w * 64)) * 8]);
            }
        }
        __syncthreads();

        #pragma unroll
        for (int h = 0; h < 2; ++h) {
            const int c = h * 4 + fsel;
            bf16x8 af[4];
            #pragma unroll
            for (int mf = 0; mf < 4; ++mf)
                af[mf] = *(const bf16x8*)&sAB[(c * 128 + wr * 64 + mf * 16 + frow) * 8];
            #pragma unroll
            for (int nf = 0; nf < 4; ++nf) {
                bf16x8 bf = *(const bf16x8*)&sAB[(1024 + c * 128 + wc * 64 + nf * 16 + frow) * 8];
                #pragma unroll
                for (int mf = 0; mf < 4; ++mf)
                    acc[mf][nf] = __builtin_amdgcn_mfma_f32_16x16x32_bf16(af[mf], bf, acc[mf][nf], 0, 0, 0);
            }
        }
    }

    // fused epilogue: gate=acc[mf][nfg], up=acc[mf][nfg+2] -> silu*pw -> Ht
    #pragma unroll
    for (int mf = 0; mf < 4; ++mf)
        #pragma unroll
        for (int nfg = 0; nfg < 2; ++nfg) {
            const int c_g = n0idx * 64 + wc * 32 + nfg * 16 + frow;   // I-col
            const size_t cb = (size_t)tile * 262144 + (size_t)(c_g >> 6) * 8192
                            + ((c_g >> 3) & 7) * 1024 + (c_g & 7);
            #pragma unroll
            for (int j = 0; j < 4; ++j) {
                int row = wr * 64 + mf * 16 + fsel * 4 + j;
                if (row < rows) {
                    float g = acc[mf][nfg][j];
                    float u = acc[mf][nfg + 2][j];
                    float sig = 1.f / (1.f + __expf(-g));
                    Ht[cb + (size_t)row * 8] = f2bf(g * sig * u * sPw[row]);
                }
            }
        }
}

// ================= GEMM2s: 128x128 tile, BK=64, m97 shape =================
__global__ __launch_bounds__(256, 4) void gemm2s_kernel(
    const short* __restrict__ Ht,       // [72][32][8][128][8]
    const short* __restrict__ Wot,      // [E][32][32][8][128][8]
    const int* __restrict__ pair_token,
    const int* __restrict__ tile_expert, const int* __restrict__ tile_row0,
    const int* __restrict__ tile_rows,
    float* __restrict__ out)            // [T][H]
{
    const int b   = blockIdx.x;          // 2304 = 72*32
    const int l   = (b & 7) * 288 + (b >> 3);
    const int tile  = l >> 5;
    const int n0idx = l & 31;            // over H/128
    const int rows = tile_rows[tile];
    if (rows == 0) return;
    const int e    = tile_expert[tile];
    const int row0 = tile_row0[tile];

    __shared__ short sAB[2048 * 8];      // 32 KB
    __shared__ int   sTok[128];

    const int tid  = threadIdx.x;
    const int lane = tid & 63;
    const int w    = tid >> 6;

    if (tid < 128) sTok[tid] = pair_token[row0 + min(tid, rows - 1)];
    __syncthreads();

    const short* aT = Ht  + (size_t)tile * 262144;
    const short* bT = Wot + ((size_t)e * 32 + n0idx) * 262144;

    const int wr = w >> 1, wc = w & 1;
    const int frow = lane & 15, fsel = lane >> 4;

    f32x4v acc[4][4];
    #pragma unroll
    for (int mf = 0; mf < 4; ++mf)
        #pragma unroll
        for (int nf = 0; nf < 4; ++nf) acc[mf][nf] = (f32x4v)0.f;

    const int KT = I_DIM / 64;           // 32
    for (int kt = 0; kt < KT; ++kt) {
        __syncthreads();
        {
            const size_t ko = (size_t)kt * 8192;
            #pragma unroll
            for (int i2 = 0; i2 < 4; ++i2) {
                load_lds16(aT + ko + (size_t)tid * 8 + i2 * 2048,
                           &sAB[(i2 * 256 + w * 64) * 8]);
                load_lds16(bT + ko + (size_t)tid * 8 + i2 * 2048,
                           &sAB[((1024 + i2 * 256 + w * 64)) * 8]);
            }
        }
        __syncthreads();

        #pragma unroll
        for (int h = 0; h < 2; ++h) {
            const int c = h * 4 + fsel;
            bf16x8 af[4];
            #pragma unroll
            for (int mf = 0; mf < 4; ++mf)
                af[mf] = *(const bf16x8*)&sAB[(c * 128 + wr * 64 + mf * 16 + frow) * 8];
            #pragma unroll
            for (int nf = 0; nf < 4; ++nf) {
                bf16x8 bf = *(const bf16x8*)&sAB[(1024 + c * 128 + wc * 64 + nf * 16 + frow) * 8];
                #pragma unroll
                for (int mf = 0; mf < 4; ++mf)
                    acc[mf][nf] = __builtin_amdgcn_mfma_f32_16x16x32_bf16(af[mf], bf, acc[mf][nf], 0, 0, 0);
            }
        }
    }

    const int r4 = fsel * 4;
    #pragma unroll
    for (int mf = 0; mf < 4; ++mf)
        #pragma unroll
        for (int nf = 0; nf < 4; ++nf) {
            const int col = n0idx * 128 + wc * 64 + nf * 16 + frow;
            #pragma unroll
            for (int j = 0; j < 4; ++j) {
                int rr = wr * 64 + mf * 16 + r4 + j;
                if (rr < rows)
                    atomicAdd(out + (size_t)sTok[rr] * H_DIM + col, acc[mf][nf][j]);
            }
        }
}

// ================= FALLBACK PATH (R3) =================
__global__ __launch_bounds__(512, 2) void gemm1_kernel(
    const short* __restrict__ Xbf, const float* __restrict__ Wi0, const float* __restrict__ Wi1,
    const int* __restrict__ pair_token, const float* __restrict__ pair_w,
    const int* __restrict__ t1_expert, const int* __restrict__ t1_row0, const int* __restrict__ t1_rows,
    short* __restrict__ Hbuf)
{
    const int tile = blockIdx.x;
    const int rows = t1_rows[tile];
    if (rows == 0) return;
    const int e    = t1_expert[tile];
    const int row0 = t1_row0[tile];
    const int n0   = blockIdx.y * BN1;

    __shared__ short sA [2][BM1][64];
    __shared__ short sB0[2][BN1][64 + 8];
    __shared__ short sB1[2][BN1][64 + 8];
    __shared__ int   sTok[BM1];
    __shared__ float sPw [BM1];

    const int tid  = threadIdx.x;
    const int lane = tid & 63;
    const int w    = tid >> 6;

    if (tid < BM1) {
        int tr = min(tid, rows - 1);
        sTok[tid] = pair_token[row0 + tr];
        sPw[tid]  = (tid < rows) ? pair_w[row0 + tid] : 0.f;
    }
    __syncthreads();

    const short* aSrc[4];
    #pragma unroll
    for (int i = 0; i < 4; ++i) {
        int r = w * 32 + i * 8 + (lane >> 3);
        int j = lane & 7;
        aSrc[i] = Xbf + (size_t)sTok[r] * H_DIM + ((j ^ (r & 7)) * 8);
    }

    const int brow = tid >> 2;
    const int bq   = tid & 3;
    const size_t wboff = ((size_t)e * I_DIM + (n0 + brow)) * H_DIM + bq * 16;
    const float* b0p = Wi0 + wboff;
    const float* b1p = Wi1 + wboff;

    const int wr   = w >> 1;
    const int wc   = w & 1;
    const int frow = lane & 15;
    const int fsel = lane >> 4;

    f32x4v accg[4][4], accu[4][4];
    #pragma unroll
    for (int mf = 0; mf < 4; ++mf)
        #pragma unroll
        for (int nf = 0; nf < 4; ++nf) { accg[mf][nf] = (f32x4v)0.f; accu[mf][nf] = (f32x4v)0.f; }

    f32x4v rb0[4], rb1[4];

    #pragma unroll
    for (int i = 0; i < 4; ++i)
        load_lds16(aSrc[i], &sA[0][w * 32 + i * 8][0]);
    #pragma unroll
    for (int i = 0; i < 4; ++i) { rb0[i] = *(const f32x4v*)(b0p + i * 4); rb1[i] = *(const f32x4v*)(b1p + i * 4); }
    {
        short* d0 = &sB0[0][brow][bq * 16];
        *(bf16x8*)d0       = pack8(rb0[0], rb0[1]);
        *(bf16x8*)(d0 + 8) = pack8(rb0[2], rb0[3]);
        short* d1 = &sB1[0][brow][bq * 16];
        *(bf16x8*)d1       = pack8(rb1[0], rb1[1]);
        *(bf16x8*)(d1 + 8) = pack8(rb1[2], rb1[3]);
    }
    __syncthreads();

    const int KT = H_DIM / 64;
    for (int kt = 0; kt < KT; ++kt) {
        const int cur = kt & 1, nxt = cur ^ 1;
        if (kt + 1 < KT) {
            #pragma unroll
            for (int i = 0; i < 4; ++i)
                load_lds16(aSrc[i] + (kt + 1) * 64, &sA[nxt][w * 32 + i * 8][0]);
            const float* p0 = b0p + (kt + 1) * 64;
            const float* p1 = b1p + (kt + 1) * 64;
            #pragma unroll
            for (int i = 0; i < 4; ++i) { rb0[i] = *(const f32x4v*)(p0 + i * 4); rb1[i] = *(const f32x4v*)(p1 + i * 4); }
        }
        #pragma unroll
        for (int h = 0; h < 2; ++h) {
            bf16x8 af[4], b0f[4], b1f[4];
            #pragma unroll
            for (int mf = 0; mf < 4; ++mf) {
                int ar = wr * 64 + mf * 16 + frow;
                int c  = (h * 4 + fsel) ^ (ar & 7);
                af[mf] = *(const bf16x8*)((const char*)&sA[cur][0][0] + ar * 128 + c * 16);
            }
            #pragma unroll
            for (int nf = 0; nf < 4; ++nf) {
                int br = wc * 64 + nf * 16 + frow;
                b0f[nf] = *(const bf16x8*)&sB0[cur][br][h * 32 + fsel * 8];
                b1f[nf] = *(const bf16x8*)&sB1[cur][br][h * 32 + fsel * 8];
            }
            #pragma unroll
            for (int nf = 0; nf < 4; ++nf)
                #pragma unroll
                for (int mf = 0; mf < 4; ++mf) {
                    accg[mf][nf] = __builtin_amdgcn_mfma_f32_16x16x32_bf16(af[mf], b0f[nf], accg[mf][nf], 0, 0, 0);
                    accu[mf][nf] = __builtin_amdgcn_mfma_f32_16x16x32_bf16(af[mf], b1f[nf], accu[mf][nf], 0, 0, 0);
                }
        }
        if (kt + 1 < KT) {
            short* d0 = &sB0[nxt][brow][bq * 16];
            *(bf16x8*)d0       = pack8(rb0[0], rb0[1]);
            *(bf16x8*)(d0 + 8) = pack8(rb0[2], rb0[3]);
            short* d1 = &sB1[nxt][brow][bq * 16];
            *(bf16x8*)d1       = pack8(rb1[0], rb1[1]);
            *(bf16x8*)(d1 + 8) = pack8(rb1[2], rb1[3]);
        }
        __syncthreads();
    }

    const int r4 = fsel * 4;
    #pragma unroll
    for (int mf = 0; mf < 4; ++mf)
        #pragma unroll
        for (int nf = 0; nf < 4; ++nf)
            #pragma unroll
            for (int j = 0; j < 4; ++j) {
                int rr = wr * 64 + mf * 16 + r4 + j;
                if (rr < rows) {
                    float g = accg[mf][nf][j];
                    float u = accu[mf][nf][j];
                    float sig = 1.f / (1.f + __expf(-g));
                    float v = g * sig * u * sPw[rr];
                    int col = n0 + wc * 64 + nf * 16 + frow;
                    Hbuf[(size_t)(row0 + rr) * I_DIM + col] = f2bf(v);
                }
            }
}

__global__ __launch_bounds__(256, 2) void gemm2_kernel(
    const short* __restrict__ Hbuf, const float* __restrict__ Wo,
    const int* __restrict__ pair_token,
    const int* __restrict__ tile_expert, const int* __restrict__ tile_row0,
    const int* __restrict__ tile_rows,
    float* __restrict__ out)
{
    const int tile = blockIdx.x;
    const int rows = tile_rows[tile];
    if (rows == 0) return;
    const int e    = tile_expert[tile];
    const int row0 = tile_row0[tile];
    const int n0   = blockIdx.y * 256;

    __shared__ short sA[BM][BK + 8];
    __shared__ short sB[256][BK + 8];
    __shared__ int   sTok[BM];

    const int tid = threadIdx.x;
    if (tid < BM) sTok[tid] = pair_token[row0 + min(tid, rows - 1)];
    __syncthreads();

    const int srow  = tid >> 1;
    const int shalf = tid & 1;

    const short* aptr = Hbuf + (size_t)(row0 + min(srow, rows - 1)) * I_DIM + shalf * 16;
    const float* bptrA = Wo + ((size_t)e * H_DIM + (n0 + srow))       * I_DIM + shalf * 16;
    const float* bptrB = Wo + ((size_t)e * H_DIM + (n0 + srow + 128)) * I_DIM + shalf * 16;

    bf16x8 ra[2];
    f32x4v rbA[4], rbB[4];
    f32x4v acc[4][8];
    #pragma unroll
    for (int mf = 0; mf < 4; ++mf)
        #pragma unroll
        for (int nf = 0; nf < 8; ++nf) acc[mf][nf] = (f32x4v)0.f;

    const int lane = tid & 63;
    const int wid  = tid >> 6;
    const int wr   = wid >> 1;
    const int wc   = wid & 1;
    const int frow = lane & 15;
    const int fk   = (lane >> 4) * 8;

    ra[0] = *(const bf16x8*)(aptr);
    ra[1] = *(const bf16x8*)(aptr + 8);
    #pragma unroll
    for (int i = 0; i < 4; ++i) { rbA[i] = *(const f32x4v*)(bptrA + i * 4); rbB[i] = *(const f32x4v*)(bptrB + i * 4); }

    const int KT = I_DIM / BK;
    for (int kt = 0; kt < KT; ++kt) {
        __syncthreads();
        *(bf16x8*)&sA[srow][shalf * 16]           = ra[0];
        *(bf16x8*)&sA[srow][shalf * 16 + 8]       = ra[1];
        *(bf16x8*)&sB[srow][shalf * 16]           = pack8(rbA[0], rbA[1]);
        *(bf16x8*)&sB[srow][shalf * 16 + 8]       = pack8(rbA[2], rbA[3]);
        *(bf16x8*)&sB[srow + 128][shalf * 16]     = pack8(rbB[0], rbB[1]);
        *(bf16x8*)&sB[srow + 128][shalf * 16 + 8] = pack8(rbB[2], rbB[3]);
        __syncthreads();

        if (kt + 1 < KT) {
            const int k = (kt + 1) * BK;
            ra[0] = *(const bf16x8*)(aptr + k);
            ra[1] = *(const bf16x8*)(aptr + k + 8);
            #pragma unroll
            for (int i = 0; i < 4; ++i) { rbA[i] = *(const f32x4v*)(bptrA + k + i * 4); rbB[i] = *(const f32x4v*)(bptrB + k + i * 4); }
        }

        bf16x8 af[4];
        #pragma unroll
        for (int mf = 0; mf < 4; ++mf)
            af[mf] = *(const bf16x8*)&sA[wr * 64 + mf * 16 + frow][fk];
        #pragma unroll
        for (int nf = 0; nf < 8; ++nf) {
            bf16x8 bfv = *(const bf16x8*)&sB[wc * 128 + nf * 16 + frow][fk];
            #pragma unroll
            for (int mf = 0; mf < 4; ++mf)
                acc[mf][nf] = __builtin_amdgcn_mfma_f32_16x16x32_bf16(af[mf], bfv, acc[mf][nf], 0, 0, 0);
        }
    }

    const int r4 = (lane >> 4) * 4;
    #pragma unroll
    for (int mf = 0; mf < 4; ++mf)
        #pragma unroll
        for (int nf = 0; nf < 8; ++nf)
            #pragma unroll
            for (int j = 0; j < 4; ++j) {
                int rr = wr * 64 + mf * 16 + r4 + j;
                if (rr < rows) {
                    int col = n0 + wc * 128 + nf * 16 + (lane & 15);
                    atomicAdd(out + (size_t)sTok[rr] * H_DIM + col, acc[mf][nf][j]);
                }
            }
}

// ---------------- launch ----------------
extern "C" void kernel_launch(void* const* d_in, const int* in_sizes, int n_in,
                              void* d_out, int out_size, void* d_ws, size_t ws_size,
                              hipStream_t stream)
{
    (void)in_sizes; (void)n_in;
    const float* X     = (const float*)d_in[0];
    const float* topw  = (const float*)d_in[1];
    const int*   topid = (const int*)d_in[2];
    const float* Wi0   = (const float*)d_in[3];
    const float* Wi1   = (const float*)d_in[4];
    const float* Wo    = (const float*)d_in[5];
    float* out = (float*)d_out;

    char* ws = (char*)d_ws;
    int*   pair_token  = (int*)ws;
    float* pair_w      = (float*)(ws + NPAIR * 4);
    int*   tile_expert = (int*)(ws + NPAIR * 8);
    int*   tile_row0   = tile_expert + MAXT;
    int*   tile_rows   = tile_row0 + MAXT;
    int*   t1_expert   = tile_rows + MAXT;
    int*   t1_row0     = t1_expert + MAXT1;
    int*   t1_rows     = t1_row0 + MAXT1;

    route_kernel<<<1, 256, 0, stream>>>(topid, topw, pair_token, pair_w,
                                        tile_expert, tile_row0, tile_rows,
                                        t1_expert, t1_row0, t1_rows);

    if (ws_size >= NEED_NEW) {
        short* Ht  = (short*)(ws + HT_OFF);
        short* At  = (short*)(ws + AT_OFF);
        short* Ws  = (short*)(ws + WS_OFF);
        short* Wot = (short*)(ws + W0_OFF);   // overlays At/Ws (dead after gemm1f)

        prep12_kernel<<<2304 + 8192, 256, 0, stream>>>(
            X, pair_token, tile_row0, tile_rows, At, Wi0, Wi1, Ws);

        gemm1f_kernel<<<2304, 256, 0, stream>>>(
            At, Ws, pair_w, tile_expert, tile_row0, tile_rows, Ht);

        hipMemsetAsync(d_out, 0, (size_t)out_size * sizeof(float), stream);

        woprep2_kernel<<<4096, 256, 0, stream>>>(Wo, Wot);

        gemm2s_kernel<<<2304, 256, 0, stream>>>(
            Ht, Wot, pair_token, tile_expert, tile_row0, tile_rows, out);
    } else {
        short* Hbuf = (short*)(ws + (1 << 20));
        short* Xbf  = (short*)d_out;

        cvt_kernel<<<T_TOK * H_DIM / (256 * 8), 256, 0, stream>>>(X, Xbf);

        gemm1_kernel<<<dim3(MAXT1, I_DIM / BN1), 512, 0, stream>>>(
            Xbf, Wi0, Wi1, pair_token, pair_w, t1_expert, t1_row0, t1_rows, Hbuf);

        hipMemsetAsync(d_out, 0, (size_t)out_size * sizeof(float), stream);

        gemm2_kernel<<<dim3(MAXT, H_DIM / 256), 256, 0, stream>>>(
            Hbuf, Wo, pair_token, tile_expert, tile_row0, tile_rows, out);
    }
}